// Round 10
// baseline (294.565 us; speedup 1.0000x reference)
//
#include <hip/hip_runtime.h>
#include <math.h>

#define B_ 2
#define L_ 2048
#define E_ 1024
#define N_ 16
#define R_ 64
#define PWP 128        // padded params pitch (96 -> 128)
#define BL_ (B_*L_)    // 4096

using bf16x8 = __attribute__((ext_vector_type(8))) short;
using f32x4  = __attribute__((ext_vector_type(4))) float;

__device__ __forceinline__ float softplusf(float x) {
    return fmaxf(x, 0.0f) + log1pf(expf(-fabsf(x)));
}
__device__ __forceinline__ float siluf(float x) {
    return x / (1.0f + expf(-x));
}
__device__ __forceinline__ ushort f2bf(float f) {
    unsigned u = __float_as_uint(f);
    return (ushort)((u + 0x7fffu + ((u >> 16) & 1u)) >> 16);
}
__device__ __forceinline__ float bf2f(ushort h) {
    return __uint_as_float(((unsigned)h) << 16);
}
__device__ __forceinline__ void gload16(const ushort* g, ushort* l) {
    __builtin_amdgcn_global_load_lds((const __attribute__((address_space(1))) void*)g,
                                     (__attribute__((address_space(3))) void*)l, 16, 0, 0);
}

// fp32 [rows_src][spitch] -> [rows_dst][2K] bf16 as [hi(K)|lo(K)]; pad rows zero.
__device__ __forceinline__ void split_body(const float* __restrict__ src, int spitch,
                                           int rows_src, ushort* __restrict__ dst,
                                           int K, int total4, int idx) {
    if (idx >= total4) return;
    const int Kq = K >> 2;
    const int r  = idx / Kq;
    const int c4 = (idx - r * Kq) << 2;
    float f[4] = {0.f, 0.f, 0.f, 0.f};
    if (r < rows_src)
        *reinterpret_cast<float4*>(f) = *reinterpret_cast<const float4*>(src + (size_t)r * spitch + c4);
    ushort h[4], lo[4];
#pragma unroll
    for (int q = 0; q < 4; ++q) {
        h[q]  = f2bf(f[q]);
        lo[q] = f2bf(f[q] - bf2f(h[q]));
    }
    ushort* d0 = dst + (size_t)r * 2 * K + c4;
    *reinterpret_cast<uint2*>(d0)     = make_uint2((uint)h[0]  | ((uint)h[1]  << 16), (uint)h[2]  | ((uint)h[3]  << 16));
    *reinterpret_cast<uint2*>(d0 + K) = make_uint2((uint)lo[0] | ((uint)lo[1] << 16), (uint)lo[2] | ((uint)lo[3] << 16));
}

__global__ __launch_bounds__(256)
void split_rm(const float* __restrict__ src, int spitch, int rows_src,
              ushort* __restrict__ dst, int K, int total4) {
    split_body(src, spitch, rows_src, dst, K, total4, blockIdx.x * 256 + threadIdx.x);
}

// merged W_z / W_p / W_dt splits (blockIdx.y selects the job)
__global__ __launch_bounds__(256)
void split_w3(const float* __restrict__ Wz, const float* __restrict__ Wp,
              const float* __restrict__ Wdt, ushort* __restrict__ WzC,
              ushort* __restrict__ WpC, ushort* __restrict__ WdtC) {
    const int idx = blockIdx.x * 256 + threadIdx.x;
    if (blockIdx.y == 0)      split_body(Wz,  E_, E_,  WzC,  E_, E_ * E_ / 4, idx);
    else if (blockIdx.y == 1) split_body(Wp,  E_, 96,  WpC,  E_, 128 * E_ / 4, idx);
    else                      split_body(Wdt, R_, E_,  WdtC, R_, E_ * R_ / 4, idx);
}

// ygT[b][e][l] fp32 -> Ycat [b*L+l][2E] bf16 hi|lo
__global__ __launch_bounds__(256)
void split_tr(const float* __restrict__ ygT, ushort* __restrict__ Ycat) {
    __shared__ float Ts[64][65];
    const int e0 = blockIdx.x * 64;
    const int l0 = blockIdx.y * 64;
    const int b  = blockIdx.z;
    const int tid = threadIdx.x;
    for (int idx = tid; idx < 64 * 64; idx += 256) {
        const int rr = idx >> 6, cc = idx & 63;
        Ts[rr][cc] = ygT[((size_t)(b * E_ + e0 + rr) << 11) + l0 + cc];
    }
    __syncthreads();
    for (int idx = tid; idx < 64 * 16; idx += 256) {
        const int rl = idx >> 4, g = idx & 15;
        ushort h[4], lo[4];
#pragma unroll
        for (int q = 0; q < 4; ++q) {
            const float f = Ts[g * 4 + q][rl];
            h[q]  = f2bf(f);
            lo[q] = f2bf(f - bf2f(h[q]));
        }
        ushort* d0 = Ycat + (size_t)(b * L_ + l0 + rl) * 2 * E_ + e0 + g * 4;
        *reinterpret_cast<uint2*>(d0)      = make_uint2((uint)h[0]  | ((uint)h[1]  << 16), (uint)h[2]  | ((uint)h[3]  << 16));
        *reinterpret_cast<uint2*>(d0 + E_) = make_uint2((uint)lo[0] | ((uint)lo[1] << 16), (uint)lo[2] | ((uint)lo[3] << 16));
    }
}

// Split-bf16 MFMA GEMM, templated BK (64/128), XOR-swizzled LDS both sides.
// Segments: A reads (hi,hi,lo), B reads (hi,lo,hi) -> Ahi*Bhi + Ahi*Blo + Alo*Bhi.
// MODE 0: C[m*Ncols+n]; MODE 1: C[((b*E+e)<<11)+l]; MODE 2: MODE1+softplus(v+bias[e]);
// MODE 3: params epilogue — fp32 C cols [80,96) + hi|lo bf16 of cols [0,64) into P2.
template<int BM, int BN, int BK, int MODE>
__global__ __launch_bounds__(256)
void mfma_gemm(const ushort* __restrict__ A, const ushort* __restrict__ Bm,
               const float* __restrict__ bias, ushort* __restrict__ P2,
               float* __restrict__ C, int Kd, int Ncols) {
    constexpr int WTM = BM / 2, WTN = BN / 2;
    constexpr int MI = WTM / 16, NJ = WTN / 16;
    constexpr int CPR = BK / 8;              // 16B chunks per LDS row
    constexpr int KS  = BK / 32;             // mfma k-steps per phase
    constexpr int RPW = 64 / CPR;            // rows staged per wave per group
    __shared__ ushort As[BM * BK];
    __shared__ ushort Bs[BN * BK];
    const int tid  = threadIdx.x;
    const int wave = tid >> 6, lane = tid & 63;
    const int m0 = blockIdx.x * BM, n0 = blockIdx.y * BN;
    const int wr = wave >> 1, wc = wave & 1;
    const int fr = lane & 15, fg = lane >> 4;
    const int kxor = (fr & 7) << 3;          // ds_read swizzle (shorts, chunk low-3 bits)
    const int pK = 2 * Kd;

    f32x4 acc[MI][NJ];
#pragma unroll
    for (int i = 0; i < MI; ++i)
#pragma unroll
        for (int j = 0; j < NJ; ++j) { f32x4 z = {0.f, 0.f, 0.f, 0.f}; acc[i][j] = z; }

    const int lrow = lane / CPR;             // 0..RPW-1
    const int lc   = lane % CPR;             // chunk idx in row

    const int KP = Kd / BK;                  // phases per segment
    for (int seg = 0; seg < 3; ++seg) {
        const int ao = (seg == 2) ? Kd : 0;  // A: hi,hi,lo
        const int bo = (seg == 1) ? Kd : 0;  // B: hi,lo,hi
        for (int tt = 0; tt < KP; ++tt) {
            const int ka = ao + tt * BK, kb = bo + tt * BK;
#pragma unroll
            for (int g = 0; g < BM / (4 * RPW); ++g) {
                const int srow = (wave * (BM / (4 * RPW)) + g) * RPW + lrow;
                const int sc = (lc & 8) | ((lc ^ (srow & 7)) & 7);   // inverse swizzle on source
                gload16(A + (size_t)(m0 + srow) * pK + ka + sc * 8, As + srow * BK + lc * 8);
            }
#pragma unroll
            for (int g = 0; g < BN / (4 * RPW); ++g) {
                const int srow = (wave * (BN / (4 * RPW)) + g) * RPW + lrow;
                const int sc = (lc & 8) | ((lc ^ (srow & 7)) & 7);
                gload16(Bm + (size_t)(n0 + srow) * pK + kb + sc * 8, Bs + srow * BK + lc * 8);
            }
            __syncthreads();

#pragma unroll
            for (int ks = 0; ks < KS; ++ks) {
                bf16x8 av[MI], bv[NJ];
#pragma unroll
                for (int i = 0; i < MI; ++i) {
                    const int row = wr * WTM + i * 16 + fr;
                    av[i] = *reinterpret_cast<const bf16x8*>(&As[row * BK + ((ks * 32 + fg * 8) ^ kxor)]);
                }
#pragma unroll
                for (int j = 0; j < NJ; ++j) {
                    const int row = wc * WTN + j * 16 + fr;
                    bv[j] = *reinterpret_cast<const bf16x8*>(&Bs[row * BK + ((ks * 32 + fg * 8) ^ kxor)]);
                }
#pragma unroll
                for (int i = 0; i < MI; ++i)
#pragma unroll
                    for (int j = 0; j < NJ; ++j)
                        acc[i][j] = __builtin_amdgcn_mfma_f32_16x16x32_bf16(av[i], bv[j], acc[i][j], 0, 0, 0);
            }
            __syncthreads();
        }
    }

    if constexpr (MODE == 0) {
#pragma unroll
        for (int i = 0; i < MI; ++i) {
            const int m = m0 + wr * WTM + i * 16 + fg * 4;
#pragma unroll
            for (int j = 0; j < NJ; ++j) {
                const int n = n0 + wc * WTN + j * 16 + fr;
#pragma unroll
                for (int r = 0; r < 4; ++r)
                    C[(size_t)(m + r) * Ncols + n] = acc[i][j][r];
            }
        }
    } else if constexpr (MODE == 3) {
#pragma unroll
        for (int i = 0; i < MI; ++i) {
            const int m = m0 + wr * WTM + i * 16 + fg * 4;
#pragma unroll
            for (int j = 0; j < NJ; ++j) {
                const int n = n0 + wc * WTN + j * 16 + fr;
#pragma unroll
                for (int r = 0; r < 4; ++r) {
                    const float v = acc[i][j][r];
                    const int mm = m + r;
                    if (n < 64) {
                        const ushort hh = f2bf(v);
                        P2[(size_t)mm * 128 + n]      = hh;
                        P2[(size_t)mm * 128 + 64 + n] = f2bf(v - bf2f(hh));
                    } else if (n >= 80 && n < 96) {
                        C[(size_t)mm * Ncols + n] = v;
                    }
                }
            }
        }
    } else {
        const int b  = n0 >> 11;
        const int lb = n0 - (b << 11);
#pragma unroll
        for (int i = 0; i < MI; ++i) {
            const int e = m0 + wr * WTM + i * 16 + fg * 4;
#pragma unroll
            for (int r = 0; r < 4; ++r) {
                const float bia = (MODE == 2) ? bias[e + r] : 0.0f;
                float* row = C + ((size_t)(b * E_ + e + r) << 11) + lb;
#pragma unroll
                for (int j = 0; j < NJ; ++j) {
                    float v = acc[i][j][r];
                    if constexpr (MODE == 2) v = softplusf(v + bia);
                    row[wc * WTN + j * 16 + fr] = v;
                }
            }
        }
    }
}

// fused depthwise causal conv (K=4) + silu -> uT[b,e,l]  AND  x split -> Xcat bf16 hi|lo.
// Single read of x through LDS serves both outputs.
__global__ __launch_bounds__(256)
void conv_split_kernel(const float* __restrict__ x, const float* __restrict__ cw,
                       float* __restrict__ uT, ushort* __restrict__ Xcat) {
    __shared__ float Xt[67][65];                 // rows: l0-3 .. l0+63, cols: e
    const int e0 = blockIdx.x * 64;
    const int l0 = blockIdx.y * 64;
    const int b  = blockIdx.z;
    const int tid = threadIdx.x;
    for (int idx = tid; idx < 67 * 64; idx += 256) {
        const int row = idx >> 6, col = idx & 63;
        const int gl = l0 - 3 + row;
        Xt[row][col] = (gl >= 0) ? x[((size_t)b * L_ + gl) * E_ + e0 + col] : 0.0f;
    }
    __syncthreads();
    // conv + silu
    const int lL = tid & 63;
    const int w  = tid >> 6;
    for (int ee = w; ee < 64; ee += 4) {
        const int e = e0 + ee;
        const float w0 = cw[e*4+0], w1 = cw[e*4+1], w2 = cw[e*4+2], w3 = cw[e*4+3];
        const float v = w0*Xt[lL][ee] + w1*Xt[lL+1][ee] + w2*Xt[lL+2][ee] + w3*Xt[lL+3][ee];
        uT[((size_t)b * E_ + e) * L_ + l0 + lL] = siluf(v);
    }
    // bf16 hi|lo split of the same tile -> Xcat[b*L+l][2E]
    for (int idx = tid; idx < 64 * 16; idx += 256) {
        const int rl = idx >> 4, g = idx & 15;
        ushort h[4], lo[4];
#pragma unroll
        for (int q = 0; q < 4; ++q) {
            const float f = Xt[3 + rl][g * 4 + q];
            h[q]  = f2bf(f);
            lo[q] = f2bf(f - bf2f(h[q]));
        }
        ushort* d0 = Xcat + (size_t)(b * L_ + l0 + rl) * 2 * E_ + e0 + g * 4;
        *reinterpret_cast<uint2*>(d0)      = make_uint2((uint)h[0]  | ((uint)h[1]  << 16), (uint)h[2]  | ((uint)h[3]  << 16));
        *reinterpret_cast<uint2*>(d0 + E_) = make_uint2((uint)lo[0] | ((uint)lo[1] << 16), (uint)lo[2] | ((uint)lo[3] << 16));
    }
}

// selective scan: one block (2 waves, 128 threads) per (b,e) channel; 16 steps/thread.
// H_0 = g_0; H_{l+1} = a_l H_l + g_l; output at l uses H_l.
// Hierarchical scan: per-thread chunk transform -> wave inclusive scan ->
// 2-wave combine via LDS -> exclusive prefix applied to g_0.
// dt/u LDS-staged (pad-33); z + C_proj streamed with +1-step register prefetch;
// outputs overwrite sdt slots in place.
__global__ __launch_bounds__(128)
void scan_kernel(const float* __restrict__ dtT, const float* __restrict__ uT,
                 const float* __restrict__ zT, const float* __restrict__ params,
                 const float* __restrict__ A_log, const float* __restrict__ Dp,
                 float* __restrict__ ygT) {
    __shared__ float sdt[64 * 33];
    __shared__ float su [64 * 33];
    __shared__ float wP1[N_], wL1[N_];           // wave-0 totals
    const int c = blockIdx.x;
    const int b = c >> 10;
    const int e = c & (E_ - 1);
    const int tid  = threadIdx.x;
    const int wave = tid >> 6, lane = tid & 63;
    constexpr int CH = 16;
    constexpr float LOG2E = 1.44269504088896340736f;

    const float* dtp = dtT + ((size_t)b * E_ + e) * L_;
    const float* up  = uT  + ((size_t)b * E_ + e) * L_;
    const float* zp  = zT  + ((size_t)b * E_ + e) * L_;

    // ---- stage dt/u rows (coalesced 2KB/instr) ----
#pragma unroll
    for (int it = 0; it < 4; ++it) {
        const int l = (it * 128 + tid) * 4;
        const int slot = ((l >> 5) * 33) + (l & 31);
        float4 vd = *reinterpret_cast<const float4*>(dtp + l);
        float4 vu = *reinterpret_cast<const float4*>(up  + l);
        sdt[slot] = vd.x; sdt[slot+1] = vd.y; sdt[slot+2] = vd.z; sdt[slot+3] = vd.w;
        su [slot] = vu.x; su [slot+1] = vu.y; su [slot+2] = vu.z; su [slot+3] = vu.w;
    }

    float An2[N_], rA[N_];
    unsigned selm = 0;
#pragma unroll
    for (int n = 0; n < N_; ++n) {
        const float A = -expf(A_log[e * N_ + n]);
        An2[n] = A * LOG2E;
        if (fabsf(A) < 1e-5f) selm |= (1u << n);
        rA[n] = 1.0f / (A + 1e-10f);
    }
    const float Dv = Dp[e];
    __syncthreads();

    const int base = (tid >> 1) * 33 + (tid & 1) * 16;   // == slot(tid*16)
    // seed inputs: read after staging barrier, before any pass-2 overwrite
    const float d0 = sdt[0];
    const float u0 = su[0];

    // ---- pass 1: per-thread chunk transform T(x) = P*x + h ----
    float P[N_], h[N_];
#pragma unroll
    for (int n = 0; n < N_; ++n) { P[n] = 1.0f; h[n] = 0.0f; }
#pragma unroll 4
    for (int j = 0; j < CH; ++j) {
        const float d  = sdt[base + j];
        const float uu = su [base + j];
#pragma unroll
        for (int n = 0; n < N_; ++n) {
            const float at = __builtin_amdgcn_exp2f(d * An2[n]);
            const float bt = ((selm >> n) & 1u) ? d : (at - 1.0f) * rA[n];
            h[n] = fmaf(at, h[n], bt * uu);
            P[n] *= at;
        }
    }

    // ---- wave-level inclusive scan ----
#pragma unroll
    for (int off = 1; off < 64; off <<= 1) {
#pragma unroll
        for (int n = 0; n < N_; ++n) {
            const float Pp = __shfl_up(P[n], off);
            const float Lp = __shfl_up(h[n], off);
            if (lane >= off) {
                h[n] = fmaf(P[n], Lp, h[n]);
                P[n] *= Pp;
            }
        }
    }

    // wave-0 totals to LDS
    if (wave == 0 && lane == 63) {
#pragma unroll
        for (int n = 0; n < N_; ++n) { wP1[n] = P[n]; wL1[n] = h[n]; }
    }
    // within-wave exclusive prefix
    float cP[N_], cL[N_];
#pragma unroll
    for (int n = 0; n < N_; ++n) {
        cP[n] = __shfl_up(P[n], 1);
        cL[n] = __shfl_up(h[n], 1);
    }
    __syncthreads();

    // seed H at chunk start: compose (prev-wave total) then within-wave exclusive
#pragma unroll
    for (int n = 0; n < N_; ++n) {
        const float pl = (lane == 0) ? 1.0f : cP[n];
        const float ll = (lane == 0) ? 0.0f : cL[n];
        float fP, fL;
        if (wave == 0) { fP = pl; fL = ll; }
        else           { fP = pl * wP1[n]; fL = fmaf(pl, wL1[n], ll); }
        const float at0 = __builtin_amdgcn_exp2f(d0 * An2[n]);
        const float bt0 = ((selm >> n) & 1u) ? d0 : (at0 - 1.0f) * rA[n];
        const float g0  = bt0 * u0;
        h[n] = fmaf(fP, g0, fL);      // identity prefix for global thread 0 -> g0
    }

    // ---- pass 2 with +1-step register prefetch of C_proj and z ----
    const float* crow = params + (size_t)b * L_ * PWP + 80;   // C_proj cols [80,96)
    const int l0 = tid * CH;
    float4 pc0, pc1, pc2, pc3;
    {
        const float4* Cp4 = reinterpret_cast<const float4*>(crow + (size_t)l0 * PWP);
        pc0 = Cp4[0]; pc1 = Cp4[1]; pc2 = Cp4[2]; pc3 = Cp4[3];
    }
    float pz = zp[l0];
#pragma unroll
    for (int j = 0; j < CH; ++j) {
        float4 nc0, nc1, nc2, nc3; float nz = 0.0f;
        if (j < CH - 1) {
            const float4* Np = reinterpret_cast<const float4*>(crow + (size_t)(l0 + j + 1) * PWP);
            nc0 = Np[0]; nc1 = Np[1]; nc2 = Np[2]; nc3 = Np[3];
            nz = zp[l0 + j + 1];
        }
        const float d  = sdt[base + j];
        const float uu = su [base + j];
        float y = 0.0f;
        y = fmaf(pc0.x, h[0],  y); y = fmaf(pc0.y, h[1],  y);
        y = fmaf(pc0.z, h[2],  y); y = fmaf(pc0.w, h[3],  y);
        y = fmaf(pc1.x, h[4],  y); y = fmaf(pc1.y, h[5],  y);
        y = fmaf(pc1.z, h[6],  y); y = fmaf(pc1.w, h[7],  y);
        y = fmaf(pc2.x, h[8],  y); y = fmaf(pc2.y, h[9],  y);
        y = fmaf(pc2.z, h[10], y); y = fmaf(pc2.w, h[11], y);
        y = fmaf(pc3.x, h[12], y); y = fmaf(pc3.y, h[13], y);
        y = fmaf(pc3.z, h[14], y); y = fmaf(pc3.w, h[15], y);
        const float outv = (y + uu * Dv) * siluf(pz);
        if (j < CH - 1) {   // final update is dead (next chunk uses scan carry)
#pragma unroll
            for (int n = 0; n < N_; ++n) {
                const float at = __builtin_amdgcn_exp2f(d * An2[n]);
                const float bt = ((selm >> n) & 1u) ? d : (at - 1.0f) * rA[n];
                h[n] = fmaf(at, h[n], bt * uu);
            }
        }
        sdt[base + j] = outv;
        pc0 = nc0; pc1 = nc1; pc2 = nc2; pc3 = nc3; pz = nz;
    }
    __syncthreads();

    // ---- coalesced store of outputs ----
    float* yp = ygT + ((size_t)b * E_ + e) * L_;
#pragma unroll
    for (int it = 0; it < 4; ++it) {
        const int l = (it * 128 + tid) * 4;
        const int slot = ((l >> 5) * 33) + (l & 31);
        float4 o;
        o.x = sdt[slot]; o.y = sdt[slot+1]; o.z = sdt[slot+2]; o.w = sdt[slot+3];
        *reinterpret_cast<float4*>(yp + l) = o;
    }
}

extern "C" void kernel_launch(void* const* d_in, const int* in_sizes, int n_in,
                              void* d_out, int out_size, void* d_ws, size_t ws_size,
                              hipStream_t stream) {
    const float* x     = (const float*)d_in[0];
    const float* W_z   = (const float*)d_in[1];
    const float* W_p   = (const float*)d_in[2];
    const float* cw    = (const float*)d_in[3];
    const float* W_dt  = (const float*)d_in[4];
    const float* b_dt  = (const float*)d_in[5];
    const float* A_log = (const float*)d_in[6];
    const float* Dp    = (const float*)d_in[7];
    const float* W_out = (const float*)d_in[8];
    float* out = (float*)d_out;

    char* w = (char*)d_ws;
    ushort* Xcat   = (ushort*)(w);               // [4096][2048]  16.78 MB
    ushort* Wzcat  = (ushort*)(w + 16777216);    // [1024][2048]   4.19 MB
    ushort* Wpcat  = (ushort*)(w + 20971520);    // [128][2048]    0.52 MB
    ushort* Wdtcat = (ushort*)(w + 21495808);    // [1024][128]    0.26 MB
    ushort* Pcat   = (ushort*)(w + 21757952);    // [4096][128]    1.05 MB
    float*  params = (float*)(w + 22806528);     // [4096][128]    2.10 MB
    float*  zT     = (float*)(w + 24903680);     // 16.78 MB
    float*  dtT    = (float*)(w + 41680896);     // 16.78 MB
    float*  uT     = (float*)(w + 58458112);     // 16.78 MB
    float*  ygT    = (float*)(w + 75235328);     // 16.78 MB
    ushort* Ycat   = Xcat;                       // alias (Xcat dead by then)
    ushort* Wocat  = Wzcat;                      // alias (Wzcat dead by then)

    // fused conv+silu -> uT and x bf16 split -> Xcat (single x read)
    conv_split_kernel<<<dim3(E_ / 64, L_ / 64, B_), 256, 0, stream>>>(x, cw, uT, Xcat);
    // merged weight splits
    split_w3<<<dim3(1024, 3), 256, 0, stream>>>(W_z, W_p, W_dt, Wzcat, Wpcat, Wdtcat);
    // z = x @ W_z^T -> zT[b,e,l]   (A = W_z rows e, B = x rows bl)
    mfma_gemm<128,64,128,1><<<dim3(E_ / 128, BL_ / 64), 256, 0, stream>>>(
        Wzcat, Xcat, nullptr, nullptr, zT, E_, 0);
    // params = x @ W_p^T: fp32 C_proj cols [80,96) + bf16 hi|lo dt_unproj -> Pcat
    mfma_gemm<64,64,128,3><<<dim3(BL_ / 64, 2), 256, 0, stream>>>(
        Xcat, Wpcat, nullptr, Pcat, params, E_, PWP);
    // dt = softplus(dt_unproj @ W_dt^T + b_dt) -> dtT[b,e,l]
    mfma_gemm<128,64,64,2><<<dim3(E_ / 128, BL_ / 64), 256, 0, stream>>>(
        Wdtcat, Pcat, b_dt, nullptr, dtT, R_, 0);
    // scan -> ygT
    scan_kernel<<<B_ * E_, 128, 0, stream>>>(dtT, uT, zT, params, A_log, Dp, ygT);
    // yg split (transpose) + W_out split
    split_tr<<<dim3(E_ / 64, L_ / 64, B_), 256, 0, stream>>>(ygT, Ycat);
    split_rm<<<1024, 256, 0, stream>>>(W_out, E_, E_, Wocat, E_, E_ * E_ / 4);
    // out = yg @ W_out^T
    mfma_gemm<128,64,128,0><<<dim3(BL_ / 128, E_ / 64), 256, 0, stream>>>(
        Ycat, Wocat, nullptr, nullptr, out, E_, E_);
}

// Round 11
// 274.543 us; speedup vs baseline: 1.0729x; 1.0729x over previous
//
#include <hip/hip_runtime.h>
#include <math.h>

#define B_ 2
#define L_ 2048
#define E_ 1024
#define N_ 16
#define R_ 64
#define PWP 128        // padded params pitch (96 -> 128)
#define BL_ (B_*L_)    // 4096

using bf16x8 = __attribute__((ext_vector_type(8))) short;
using f32x4  = __attribute__((ext_vector_type(4))) float;

__device__ __forceinline__ float softplusf(float x) {
    return fmaxf(x, 0.0f) + log1pf(expf(-fabsf(x)));
}
__device__ __forceinline__ float siluf(float x) {
    return x / (1.0f + expf(-x));
}
__device__ __forceinline__ ushort f2bf(float f) {
    unsigned u = __float_as_uint(f);
    return (ushort)((u + 0x7fffu + ((u >> 16) & 1u)) >> 16);
}
__device__ __forceinline__ float bf2f(ushort h) {
    return __uint_as_float(((unsigned)h) << 16);
}
__device__ __forceinline__ void gload16(const ushort* g, ushort* l) {
    __builtin_amdgcn_global_load_lds((const __attribute__((address_space(1))) void*)g,
                                     (__attribute__((address_space(3))) void*)l, 16, 0, 0);
}

// fp32 [rows_src][spitch] -> [rows_dst][2K] bf16 as [hi(K)|lo(K)]; pad rows zero.
__device__ __forceinline__ void split_body(const float* __restrict__ src, int spitch,
                                           int rows_src, ushort* __restrict__ dst,
                                           int K, int total4, int idx) {
    if (idx >= total4) return;
    const int Kq = K >> 2;
    const int r  = idx / Kq;
    const int c4 = (idx - r * Kq) << 2;
    float f[4] = {0.f, 0.f, 0.f, 0.f};
    if (r < rows_src)
        *reinterpret_cast<float4*>(f) = *reinterpret_cast<const float4*>(src + (size_t)r * spitch + c4);
    ushort h[4], lo[4];
#pragma unroll
    for (int q = 0; q < 4; ++q) {
        h[q]  = f2bf(f[q]);
        lo[q] = f2bf(f[q] - bf2f(h[q]));
    }
    ushort* d0 = dst + (size_t)r * 2 * K + c4;
    *reinterpret_cast<uint2*>(d0)     = make_uint2((uint)h[0]  | ((uint)h[1]  << 16), (uint)h[2]  | ((uint)h[3]  << 16));
    *reinterpret_cast<uint2*>(d0 + K) = make_uint2((uint)lo[0] | ((uint)lo[1] << 16), (uint)lo[2] | ((uint)lo[3] << 16));
}

__global__ __launch_bounds__(256)
void split_rm(const float* __restrict__ src, int spitch, int rows_src,
              ushort* __restrict__ dst, int K, int total4) {
    split_body(src, spitch, rows_src, dst, K, total4, blockIdx.x * 256 + threadIdx.x);
}

// merged W_z / W_p / W_dt splits (blockIdx.y selects the job)
__global__ __launch_bounds__(256)
void split_w3(const float* __restrict__ Wz, const float* __restrict__ Wp,
              const float* __restrict__ Wdt, ushort* __restrict__ WzC,
              ushort* __restrict__ WpC, ushort* __restrict__ WdtC) {
    const int idx = blockIdx.x * 256 + threadIdx.x;
    if (blockIdx.y == 0)      split_body(Wz,  E_, E_,  WzC,  E_, E_ * E_ / 4, idx);
    else if (blockIdx.y == 1) split_body(Wp,  E_, 96,  WpC,  E_, 128 * E_ / 4, idx);
    else                      split_body(Wdt, R_, E_,  WdtC, R_, E_ * R_ / 4, idx);
}

// ygT[b][e][l] fp32 -> Ycat [b*L+l][2E] bf16 hi|lo
__global__ __launch_bounds__(256)
void split_tr(const float* __restrict__ ygT, ushort* __restrict__ Ycat) {
    __shared__ float Ts[64][65];
    const int e0 = blockIdx.x * 64;
    const int l0 = blockIdx.y * 64;
    const int b  = blockIdx.z;
    const int tid = threadIdx.x;
    for (int idx = tid; idx < 64 * 64; idx += 256) {
        const int rr = idx >> 6, cc = idx & 63;
        Ts[rr][cc] = ygT[((size_t)(b * E_ + e0 + rr) << 11) + l0 + cc];
    }
    __syncthreads();
    for (int idx = tid; idx < 64 * 16; idx += 256) {
        const int rl = idx >> 4, g = idx & 15;
        ushort h[4], lo[4];
#pragma unroll
        for (int q = 0; q < 4; ++q) {
            const float f = Ts[g * 4 + q][rl];
            h[q]  = f2bf(f);
            lo[q] = f2bf(f - bf2f(h[q]));
        }
        ushort* d0 = Ycat + (size_t)(b * L_ + l0 + rl) * 2 * E_ + e0 + g * 4;
        *reinterpret_cast<uint2*>(d0)      = make_uint2((uint)h[0]  | ((uint)h[1]  << 16), (uint)h[2]  | ((uint)h[3]  << 16));
        *reinterpret_cast<uint2*>(d0 + E_) = make_uint2((uint)lo[0] | ((uint)lo[1] << 16), (uint)lo[2] | ((uint)lo[3] << 16));
    }
}

// Split-bf16 MFMA GEMM, templated BK (64/128), XOR-swizzled LDS both sides.
// Segments: A reads (hi,hi,lo), B reads (hi,lo,hi) -> Ahi*Bhi + Ahi*Blo + Alo*Bhi.
// MODE 0: C[m*Ncols+n]
// MODE 2: dt epilogue — C[((b*E+e)<<11)+l] = softplus(v + bias[e])
// MODE 4: merged z+params — A rows [0,1024) are W_z (z transposed store to C);
//         A rows [1024,1152) are W_p: cols<64 -> hi|lo bf16 into P2[bl][128];
//         cols in [80,96) -> fp32 into C2[bl][PWP].
template<int BM, int BN, int BK, int MODE>
__global__ __launch_bounds__(256)
void mfma_gemm(const ushort* __restrict__ A, const ushort* __restrict__ Bm,
               const float* __restrict__ bias, ushort* __restrict__ P2,
               float* __restrict__ C2, float* __restrict__ C, int Kd, int Ncols) {
    constexpr int WTM = BM / 2, WTN = BN / 2;
    constexpr int MI = WTM / 16, NJ = WTN / 16;
    constexpr int CPR = BK / 8;              // 16B chunks per LDS row
    constexpr int KS  = BK / 32;             // mfma k-steps per phase
    constexpr int RPW = 64 / CPR;            // rows staged per wave per group
    __shared__ ushort As[BM * BK];
    __shared__ ushort Bs[BN * BK];
    const int tid  = threadIdx.x;
    const int wave = tid >> 6, lane = tid & 63;
    const int m0 = blockIdx.x * BM, n0 = blockIdx.y * BN;
    const int wr = wave >> 1, wc = wave & 1;
    const int fr = lane & 15, fg = lane >> 4;
    const int kxor = (fr & 7) << 3;          // ds_read swizzle (shorts, chunk low-3 bits)
    const int pK = 2 * Kd;

    f32x4 acc[MI][NJ];
#pragma unroll
    for (int i = 0; i < MI; ++i)
#pragma unroll
        for (int j = 0; j < NJ; ++j) { f32x4 z = {0.f, 0.f, 0.f, 0.f}; acc[i][j] = z; }

    const int lrow = lane / CPR;             // 0..RPW-1
    const int lc   = lane % CPR;             // chunk idx in row

    const int KP = Kd / BK;                  // phases per segment
    for (int seg = 0; seg < 3; ++seg) {
        const int ao = (seg == 2) ? Kd : 0;  // A: hi,hi,lo
        const int bo = (seg == 1) ? Kd : 0;  // B: hi,lo,hi
        for (int tt = 0; tt < KP; ++tt) {
            const int ka = ao + tt * BK, kb = bo + tt * BK;
#pragma unroll
            for (int g = 0; g < BM / (4 * RPW); ++g) {
                const int srow = (wave * (BM / (4 * RPW)) + g) * RPW + lrow;
                const int sc = (lc & 8) | ((lc ^ (srow & 7)) & 7);   // inverse swizzle on source
                gload16(A + (size_t)(m0 + srow) * pK + ka + sc * 8, As + srow * BK + lc * 8);
            }
#pragma unroll
            for (int g = 0; g < BN / (4 * RPW); ++g) {
                const int srow = (wave * (BN / (4 * RPW)) + g) * RPW + lrow;
                const int sc = (lc & 8) | ((lc ^ (srow & 7)) & 7);
                gload16(Bm + (size_t)(n0 + srow) * pK + kb + sc * 8, Bs + srow * BK + lc * 8);
            }
            __syncthreads();

#pragma unroll
            for (int ks = 0; ks < KS; ++ks) {
                bf16x8 av[MI], bv[NJ];
#pragma unroll
                for (int i = 0; i < MI; ++i) {
                    const int row = wr * WTM + i * 16 + fr;
                    av[i] = *reinterpret_cast<const bf16x8*>(&As[row * BK + ((ks * 32 + fg * 8) ^ kxor)]);
                }
#pragma unroll
                for (int j = 0; j < NJ; ++j) {
                    const int row = wc * WTN + j * 16 + fr;
                    bv[j] = *reinterpret_cast<const bf16x8*>(&Bs[row * BK + ((ks * 32 + fg * 8) ^ kxor)]);
                }
#pragma unroll
                for (int i = 0; i < MI; ++i)
#pragma unroll
                    for (int j = 0; j < NJ; ++j)
                        acc[i][j] = __builtin_amdgcn_mfma_f32_16x16x32_bf16(av[i], bv[j], acc[i][j], 0, 0, 0);
            }
            __syncthreads();
        }
    }

    if constexpr (MODE == 0) {
#pragma unroll
        for (int i = 0; i < MI; ++i) {
            const int m = m0 + wr * WTM + i * 16 + fg * 4;
#pragma unroll
            for (int j = 0; j < NJ; ++j) {
                const int n = n0 + wc * WTN + j * 16 + fr;
#pragma unroll
                for (int r = 0; r < 4; ++r)
                    C[(size_t)(m + r) * Ncols + n] = acc[i][j][r];
            }
        }
    } else if constexpr (MODE == 2) {
        const int b  = n0 >> 11;
        const int lb = n0 - (b << 11);
#pragma unroll
        for (int i = 0; i < MI; ++i) {
            const int e = m0 + wr * WTM + i * 16 + fg * 4;
#pragma unroll
            for (int r = 0; r < 4; ++r) {
                const float bia = bias[e + r];
                float* row = C + ((size_t)(b * E_ + e + r) << 11) + lb;
#pragma unroll
                for (int j = 0; j < NJ; ++j)
                    row[wc * WTN + j * 16 + fr] = softplusf(acc[i][j][r] + bia);
            }
        }
    } else {   // MODE 4
        if (m0 < 1024) {
            const int b  = n0 >> 11;
            const int lb = n0 - (b << 11);
#pragma unroll
            for (int i = 0; i < MI; ++i) {
                const int e = m0 + wr * WTM + i * 16 + fg * 4;
#pragma unroll
                for (int r = 0; r < 4; ++r) {
                    float* row = C + ((size_t)(b * E_ + e + r) << 11) + lb;
#pragma unroll
                    for (int j = 0; j < NJ; ++j)
                        row[wc * WTN + j * 16 + fr] = acc[i][j][r];
                }
            }
        } else {
#pragma unroll
            for (int i = 0; i < MI; ++i) {
                const int cb = m0 - 1024 + wr * WTM + i * 16 + fg * 4;
#pragma unroll
                for (int j = 0; j < NJ; ++j) {
                    const int bl = n0 + wc * WTN + j * 16 + fr;
#pragma unroll
                    for (int r = 0; r < 4; ++r) {
                        const float v = acc[i][j][r];
                        const int cix = cb + r;
                        if (cix < 64) {
                            const ushort hh = f2bf(v);
                            P2[(size_t)bl * 128 + cix]      = hh;
                            P2[(size_t)bl * 128 + 64 + cix] = f2bf(v - bf2f(hh));
                        } else if (cix >= 80 && cix < 96) {
                            C2[(size_t)bl * PWP + cix] = v;
                        }
                    }
                }
            }
        }
    }
}

// fused depthwise causal conv (K=4) + silu -> uT[b,e,l]  AND  x split -> Xcat bf16 hi|lo.
__global__ __launch_bounds__(256)
void conv_split_kernel(const float* __restrict__ x, const float* __restrict__ cw,
                       float* __restrict__ uT, ushort* __restrict__ Xcat) {
    __shared__ float Xt[67][65];                 // rows: l0-3 .. l0+63, cols: e
    const int e0 = blockIdx.x * 64;
    const int l0 = blockIdx.y * 64;
    const int b  = blockIdx.z;
    const int tid = threadIdx.x;
    for (int idx = tid; idx < 67 * 64; idx += 256) {
        const int row = idx >> 6, col = idx & 63;
        const int gl = l0 - 3 + row;
        Xt[row][col] = (gl >= 0) ? x[((size_t)b * L_ + gl) * E_ + e0 + col] : 0.0f;
    }
    __syncthreads();
    const int lL = tid & 63;
    const int w  = tid >> 6;
    for (int ee = w; ee < 64; ee += 4) {
        const int e = e0 + ee;
        const float w0 = cw[e*4+0], w1 = cw[e*4+1], w2 = cw[e*4+2], w3 = cw[e*4+3];
        const float v = w0*Xt[lL][ee] + w1*Xt[lL+1][ee] + w2*Xt[lL+2][ee] + w3*Xt[lL+3][ee];
        uT[((size_t)b * E_ + e) * L_ + l0 + lL] = siluf(v);
    }
    for (int idx = tid; idx < 64 * 16; idx += 256) {
        const int rl = idx >> 4, g = idx & 15;
        ushort h[4], lo[4];
#pragma unroll
        for (int q = 0; q < 4; ++q) {
            const float f = Xt[3 + rl][g * 4 + q];
            h[q]  = f2bf(f);
            lo[q] = f2bf(f - bf2f(h[q]));
        }
        ushort* d0 = Xcat + (size_t)(b * L_ + l0 + rl) * 2 * E_ + e0 + g * 4;
        *reinterpret_cast<uint2*>(d0)      = make_uint2((uint)h[0]  | ((uint)h[1]  << 16), (uint)h[2]  | ((uint)h[3]  << 16));
        *reinterpret_cast<uint2*>(d0 + E_) = make_uint2((uint)lo[0] | ((uint)lo[1] << 16), (uint)lo[2] | ((uint)lo[3] << 16));
    }
}

// selective scan: one wave per (b,e) channel (best measured config, R7).
// H_0 = g_0; H_{l+1} = a_l H_l + g_l; output at l uses H_l.
// dt/u LDS-staged (pad-33); z and C_proj streamed in pass 2 with +1-step register
// prefetch; chunk product P[n] = exp2(An2[n]*sum(d)) (prefix-product of exps = exp
// of sum); outputs overwrite sdt slots in place; coalesced final store.
__global__ __launch_bounds__(64)
void scan_kernel(const float* __restrict__ dtT, const float* __restrict__ uT,
                 const float* __restrict__ zT, const float* __restrict__ params,
                 const float* __restrict__ A_log, const float* __restrict__ Dp,
                 float* __restrict__ ygT) {
    __shared__ float sdt[64 * 33];
    __shared__ float su [64 * 33];
    const int c = blockIdx.x;
    const int b = c >> 10;
    const int e = c & (E_ - 1);
    const int lane = threadIdx.x;
    constexpr int CH = L_ / 64;   // 32
    constexpr float LOG2E = 1.44269504088896340736f;

    const float* dtp = dtT + ((size_t)b * E_ + e) * L_;
    const float* up  = uT  + ((size_t)b * E_ + e) * L_;
    const float* zp  = zT  + ((size_t)b * E_ + e) * L_;

    // ---- stage dt/u rows (coalesced 1KB/instr) ----
#pragma unroll
    for (int it = 0; it < 8; ++it) {
        const int l = (it * 64 + lane) * 4;
        const int slot = ((l >> 5) * 33) + (l & 31);
        float4 vd = *reinterpret_cast<const float4*>(dtp + l);
        float4 vu = *reinterpret_cast<const float4*>(up  + l);
        sdt[slot] = vd.x; sdt[slot+1] = vd.y; sdt[slot+2] = vd.z; sdt[slot+3] = vd.w;
        su [slot] = vu.x; su [slot+1] = vu.y; su [slot+2] = vu.z; su [slot+3] = vu.w;
    }

    float An2[N_], rA[N_];
    unsigned selm = 0;
#pragma unroll
    for (int n = 0; n < N_; ++n) {
        const float A = -expf(A_log[e * N_ + n]);
        An2[n] = A * LOG2E;
        if (fabsf(A) < 1e-5f) selm |= (1u << n);
        rA[n] = 1.0f / (A + 1e-10f);
    }
    const float Dv = Dp[e];
    __syncthreads();

    const int base = lane * 33;
    // seed inputs (broadcast reads, before any pass-2 overwrite)
    const float d0 = sdt[0];
    const float u0 = su[0];

    // ---- pass 1: per-chunk linear transform; P via exp2 of dt-sum ----
    float h[N_];
    float dsum = 0.0f;
#pragma unroll
    for (int n = 0; n < N_; ++n) h[n] = 0.0f;
#pragma unroll 4
    for (int j = 0; j < CH; ++j) {
        const float d  = sdt[base + j];
        const float uu = su [base + j];
        dsum += d;
#pragma unroll
        for (int n = 0; n < N_; ++n) {
            const float at = __builtin_amdgcn_exp2f(d * An2[n]);
            const float bt = ((selm >> n) & 1u) ? d : (at - 1.0f) * rA[n];
            h[n] = fmaf(at, h[n], bt * uu);
        }
    }
    float P[N_];
#pragma unroll
    for (int n = 0; n < N_; ++n) P[n] = __builtin_amdgcn_exp2f(dsum * An2[n]);

    // ---- inclusive wave scan of transforms ----
#pragma unroll
    for (int off = 1; off < 64; off <<= 1) {
#pragma unroll
        for (int n = 0; n < N_; ++n) {
            const float Pp = __shfl_up(P[n], off);
            const float Lp = __shfl_up(h[n], off);
            if (lane >= off) {
                h[n] = fmaf(P[n], Lp, h[n]);
                P[n] *= Pp;
            }
        }
    }

    float cP[N_], cL[N_];
#pragma unroll
    for (int n = 0; n < N_; ++n) {
        cP[n] = __shfl_up(P[n], 1);
        cL[n] = __shfl_up(h[n], 1);
    }

    // seed: H_0 = g_0
#pragma unroll
    for (int n = 0; n < N_; ++n) {
        const float at0 = __builtin_amdgcn_exp2f(d0 * An2[n]);
        const float bt0 = ((selm >> n) & 1u) ? d0 : (at0 - 1.0f) * rA[n];
        const float g0 = bt0 * u0;
        h[n] = (lane == 0) ? g0 : fmaf(cP[n], g0, cL[n]);
    }

    // ---- pass 2 with +1-step register prefetch of C_proj and z ----
    const float* crow = params + (size_t)b * L_ * PWP + 80;   // C_proj cols [80,96)
    const int l0 = lane * CH;
    float4 pc0, pc1, pc2, pc3;
    {
        const float4* Cp4 = reinterpret_cast<const float4*>(crow + (size_t)l0 * PWP);
        pc0 = Cp4[0]; pc1 = Cp4[1]; pc2 = Cp4[2]; pc3 = Cp4[3];
    }
    float pz = zp[l0];
#pragma unroll 4
    for (int j = 0; j < CH; ++j) {
        float4 nc0, nc1, nc2, nc3; float nz = 0.0f;
        if (j < CH - 1) {
            const float4* Np = reinterpret_cast<const float4*>(crow + (size_t)(l0 + j + 1) * PWP);
            nc0 = Np[0]; nc1 = Np[1]; nc2 = Np[2]; nc3 = Np[3];
            nz = zp[l0 + j + 1];
        }
        const float d  = sdt[base + j];
        const float uu = su [base + j];
        float y = 0.0f;
        y = fmaf(pc0.x, h[0],  y); y = fmaf(pc0.y, h[1],  y);
        y = fmaf(pc0.z, h[2],  y); y = fmaf(pc0.w, h[3],  y);
        y = fmaf(pc1.x, h[4],  y); y = fmaf(pc1.y, h[5],  y);
        y = fmaf(pc1.z, h[6],  y); y = fmaf(pc1.w, h[7],  y);
        y = fmaf(pc2.x, h[8],  y); y = fmaf(pc2.y, h[9],  y);
        y = fmaf(pc2.z, h[10], y); y = fmaf(pc2.w, h[11], y);
        y = fmaf(pc3.x, h[12], y); y = fmaf(pc3.y, h[13], y);
        y = fmaf(pc3.z, h[14], y); y = fmaf(pc3.w, h[15], y);
        const float outv = (y + uu * Dv) * siluf(pz);
        if (j < CH - 1) {   // final update is dead
#pragma unroll
            for (int n = 0; n < N_; ++n) {
                const float at = __builtin_amdgcn_exp2f(d * An2[n]);
                const float bt = ((selm >> n) & 1u) ? d : (at - 1.0f) * rA[n];
                h[n] = fmaf(at, h[n], bt * uu);
            }
        }
        sdt[base + j] = outv;
        pc0 = nc0; pc1 = nc1; pc2 = nc2; pc3 = nc3; pz = nz;
    }
    __syncthreads();

    // ---- coalesced store of outputs ----
    float* yp = ygT + ((size_t)b * E_ + e) * L_;
#pragma unroll
    for (int it = 0; it < 8; ++it) {
        const int l = (it * 64 + lane) * 4;
        const int slot = ((l >> 5) * 33) + (l & 31);
        float4 o;
        o.x = sdt[slot]; o.y = sdt[slot+1]; o.z = sdt[slot+2]; o.w = sdt[slot+3];
        *reinterpret_cast<float4*>(yp + l) = o;
    }
}

extern "C" void kernel_launch(void* const* d_in, const int* in_sizes, int n_in,
                              void* d_out, int out_size, void* d_ws, size_t ws_size,
                              hipStream_t stream) {
    const float* x     = (const float*)d_in[0];
    const float* W_z   = (const float*)d_in[1];
    const float* W_p   = (const float*)d_in[2];
    const float* cw    = (const float*)d_in[3];
    const float* W_dt  = (const float*)d_in[4];
    const float* b_dt  = (const float*)d_in[5];
    const float* A_log = (const float*)d_in[6];
    const float* Dp    = (const float*)d_in[7];
    const float* W_out = (const float*)d_in[8];
    float* out = (float*)d_out;

    char* w = (char*)d_ws;
    ushort* Xcat   = (ushort*)(w);               // [4096][2048]  16.78 MB
    ushort* Wzpcat = (ushort*)(w + 16777216);    // [1152][2048]   4.72 MB (Wz rows 0..1023, Wp rows 1024..1151)
    ushort* Wpcat  = (ushort*)(w + 20971520);    // = Wzpcat + 1024 rows
    ushort* Wdtcat = (ushort*)(w + 21495808);    // [1024][128]    0.26 MB
    ushort* Pcat   = (ushort*)(w + 21757952);    // [4096][128]    1.05 MB
    float*  params = (float*)(w + 22806528);     // [4096][128]    2.10 MB
    float*  zT     = (float*)(w + 24903680);     // 16.78 MB
    float*  dtT    = (float*)(w + 41680896);     // 16.78 MB
    float*  uT     = (float*)(w + 58458112);     // 16.78 MB
    float*  ygT    = (float*)(w + 75235328);     // 16.78 MB
    ushort* Ycat   = Xcat;                       // alias (Xcat dead by then)
    ushort* Wocat  = Wzpcat;                     // alias (Wzpcat dead by then)

    // fused conv+silu -> uT and x bf16 split -> Xcat (single x read)
    conv_split_kernel<<<dim3(E_ / 64, L_ / 64, B_), 256, 0, stream>>>(x, cw, uT, Xcat);
    // merged weight splits (Wp lands directly after Wz -> stacked A of 1152 rows)
    split_w3<<<dim3(1024, 3), 256, 0, stream>>>(W_z, W_p, W_dt, Wzpcat, Wpcat, Wdtcat);
    // merged z+params GEMM: zT[b,e,l], Pcat (bf16 hi|lo dt_unproj), params C_proj cols
    mfma_gemm<128,64,128,4><<<dim3(1152 / 128, BL_ / 64), 256, 0, stream>>>(
        Wzpcat, Xcat, nullptr, Pcat, params, zT, E_, 0);
    // dt = softplus(dt_unproj @ W_dt^T + b_dt) -> dtT[b,e,l]
    mfma_gemm<128,64,64,2><<<dim3(E_ / 128, BL_ / 64), 256, 0, stream>>>(
        Wdtcat, Pcat, b_dt, nullptr, nullptr, dtT, R_, 0);
    // scan -> ygT
    scan_kernel<<<B_ * E_, 64, 0, stream>>>(dtT, uT, zT, params, A_log, Dp, ygT);
    // yg split (transpose) + W_out split
    split_tr<<<dim3(E_ / 64, L_ / 64, B_), 256, 0, stream>>>(ygT, Ycat);
    split_rm<<<1024, 256, 0, stream>>>(W_out, E_, E_, Wocat, E_, E_ * E_ / 4);
    // out = yg @ W_out^T
    mfma_gemm<128,64,128,0><<<dim3(BL_ / 128, E_ / 64), 256, 0, stream>>>(
        Ycat, Wocat, nullptr, nullptr, nullptr, out, E_, E_);
}